// Round 10
// baseline (300.118 us; speedup 1.0000x reference)
//
#include <hip/hip_runtime.h>
#include <hip/hip_bf16.h>
#include <hip/hip_fp16.h>

// NLBlockND (embedded non-local block), MI355X/gfx950.
// Round 17: two changes on the round-16 base (280.6 us, flash 107.6):
//  (1) gemm_nt: double-buffered staging (flash round-10 pattern): 32 KB LDS,
//      ONE barrier per k-step, STAGE(next) issued right after the barrier ->
//      stage latency hidden under the 16 MFMAs; barrier count halved.
//      The 3 GEMMs (21.5 GF) were ~105 us of the 173 us non-flash time.
//  (2) flash: QK^T split into two independent 8-MFMA chains (svx+svy) and
//      the 8 V-fragments batch-loaded before each PV MFMA run. VGPR 128->
//      ~190 is FREE (occupancy is LDS-capped at 2 blocks/CU, cap 256).
// Round-9..16 lessons kept: raw v_exp_f32 (exp2f is precise libm = ~9 ops),
// no setprio (m190 regime), sequential reductions, thr 11.5 log2 = 8 nats.
// Shapes: N=4, C=512, CI=256, L=4096.

#define NB    4
#define CDIM  512
#define CIDIM 256
#define LDIM  4096
#define BN_EPS 1e-5f
#define LOG2E 1.4426950408889634f

typedef unsigned short u16;
typedef __attribute__((ext_vector_type(8))) short short8;    // 8 bf16 (4 VGPRs)
typedef __attribute__((ext_vector_type(4))) float f32x4;     // 16x16 MFMA C/D
typedef __attribute__((ext_vector_type(16))) float f32x16;   // 32x32 MFMA C/D

// Workspace (float offsets). WY region hosts, in sequence: xT (bf16, dies
// after projections) -> OPB partials (bf16, die after merge) -> WY (fp32).
#define WY_OFF    0                  // 8,388,608 floats
#define THPH_OFF  8388608            // 4,194,304 floats (N,L,512 bf16 [theta|phi])
#define G_OFF     12582912           // 2,097,152 floats (g bf16, (N,CI,L))
#define Y_OFF     14680064           // 2,097,152 floats (yT bf16, (N,L,CI))
#define WTS_OFF   16777216           //   262,144 floats = 524,288 bf16 weights
#define BIAS2_OFF 17039360           //       512 floats ([tb|pb])
#define ML_OFF    17039872           //    65,536 floats (4 quarters x N*L half2)
#define ST_OFF    17105408           //     1,024 floats
// total 17,106,432 floats = 68.4 MB (unchanged)

__device__ __forceinline__ u16 f2b(float f) {  // fp32 -> bf16 RNE
    union { float f; unsigned u; } v; v.f = f;
    return (u16)((v.u + 0x7FFFu + ((v.u >> 16) & 1u)) >> 16);
}

__device__ __forceinline__ float b2f(u16 x) {
    return __uint_as_float((unsigned)x << 16);
}

__device__ __forceinline__ unsigned pack2(float a, float b) {
    return (unsigned)f2b(a) | ((unsigned)f2b(b) << 16);
}

// raw hardware exp2: one v_exp_f32, no denormal fixup (fine for softmax P)
__device__ __forceinline__ float fast_exp2(float x) {
#if __has_builtin(__builtin_amdgcn_exp2f)
    return __builtin_amdgcn_exp2f(x);
#else
    float r; asm("v_exp_f32 %0, %1" : "=v"(r) : "v"(x)); return r;
#endif
}

__device__ __forceinline__ void gl_lds16(const u16* g, u16* l) {
    __builtin_amdgcn_global_load_lds(
        (const __attribute__((address_space(1))) void*)g,
        (__attribute__((address_space(3))) void*)l, 16, 0, 0);
}

// ---------------------------------------------------------------------------
// x (N,C,L) fp32 -> xT (N,L,C) bf16.  32x32 LDS tiles.
// ---------------------------------------------------------------------------
__global__ void transpose_x(const float* __restrict__ x, u16* __restrict__ xt) {
    __shared__ float tile[32][33];
    int n = blockIdx.z;
    int l0 = blockIdx.x * 32, c0 = blockIdx.y * 32;
    const float* xn = x + (size_t)n * CDIM * LDIM;
    u16* xtn = xt + (size_t)n * LDIM * CDIM;
    int tx = threadIdx.x, ty = threadIdx.y;  // (32, 8)
#pragma unroll
    for (int k = 0; k < 4; k++)
        tile[ty + 8 * k][tx] = xn[(size_t)(c0 + ty + 8 * k) * LDIM + l0 + tx];
    __syncthreads();
#pragma unroll
    for (int k = 0; k < 4; k++)
        xtn[(size_t)(l0 + ty + 8 * k) * CDIM + c0 + tx] = f2b(tile[tx][ty + 8 * k]);
}

// ---------------------------------------------------------------------------
// Cast the 4 weight matrices (each 131072 fp32) to bf16, concatenated;
// theta (seg 1) pre-scaled by log2(e) so flash softmax uses exp2 directly.
// Tail blocks also build the [tb*log2e | pb] fp32 bias concat (one launch).
// ---------------------------------------------------------------------------
__global__ void cast_w(const float* __restrict__ gw, const float* __restrict__ tw,
                       const float* __restrict__ pw, const float* __restrict__ zw,
                       u16* __restrict__ out,
                       const float* __restrict__ tb, const float* __restrict__ pb,
                       float* __restrict__ bc) {
    int idx = blockIdx.x * 256 + threadIdx.x;
    if (idx < 4 * 131072) {
        int seg = idx >> 17, off = idx & 131071;
        const float* s = (seg == 0) ? gw : (seg == 1) ? tw : (seg == 2) ? pw : zw;
        float v = s[off];
        if (seg == 1) v *= LOG2E;
        out[idx] = f2b(v);
    } else {
        int i = idx - 4 * 131072;
        if (i < 256) bc[i] = tb[i] * LOG2E;
        else if (i < 512) bc[i] = pb[i - 256];
    }
}

// ---------------------------------------------------------------------------
// NT-GEMM: D[m][n] = sum_k A[m][k]*B[n][k] (+bias). 128x128 tile, BK=32,
// 256 threads (4 waves 2x2), 16x16x32 bf16 MFMA, global_load_lds staging,
// slot^row&3 swizzle. Round-17: DOUBLE-BUFFERED staging (32 KB LDS): one
// barrier per k-step, STAGE(next) issued right after (stage hidden under
// the 16 MFMAs) — the verified flash round-10 pattern.
// ---------------------------------------------------------------------------
template <int BIAS_MODE, bool OUT_BF16>
__global__ __launch_bounds__(256)
void gemm_nt(const u16* __restrict__ A, const u16* __restrict__ B,
             void* __restrict__ Dv, const float* __restrict__ bias,
             int K, int lda, int ldb, int ldd,
             long batchA, long batchB, long batchD) {
    __shared__ __align__(16) u16 As[2][128 * 32];
    __shared__ __align__(16) u16 Bs[2][128 * 32];
    int z = blockIdx.z;
    A += (size_t)z * batchA;
    B += (size_t)z * batchB;

    int tid = threadIdx.x, lane = tid & 63, wave = tid >> 6;
    int n0 = blockIdx.x * 128, m0 = blockIdx.y * 128;
    int wr = wave >> 1, wc = wave & 1;

    f32x4 acc[4][4];
#pragma unroll
    for (int i = 0; i < 4; i++)
#pragma unroll
        for (int j = 0; j < 4; j++) acc[i][j] = (f32x4){0.f, 0.f, 0.f, 0.f};

    int sr = wave * 16 + (lane >> 2);
    int ss = ((lane & 3) ^ ((lane >> 2) & 3)) * 8;
    const u16* Ag0 = A + (size_t)(m0 + sr) * lda + ss;
    const u16* Ag1 = A + (size_t)(m0 + 64 + sr) * lda + ss;
    const u16* Bg0 = B + (size_t)(n0 + sr) * ldb + ss;
    const u16* Bg1 = B + (size_t)(n0 + 64 + sr) * ldb + ss;
    int sdst = wave * 16 * 32;           // wave's quarter; +2048 = +64 rows

    int koff = ((lane >> 4) ^ (lane & 3)) * 8;
    int ra = (wr * 64 + (lane & 15)) * 32 + koff;
    int rb = (wc * 64 + (lane & 15)) * 32 + koff;

#define GSTAGE(bi, k0_) do {                                                   \
    gl_lds16(Ag0 + (k0_), &As[bi][sdst]);                                      \
    gl_lds16(Ag1 + (k0_), &As[bi][sdst + 2048]);                               \
    gl_lds16(Bg0 + (k0_), &Bs[bi][sdst]);                                      \
    gl_lds16(Bg1 + (k0_), &Bs[bi][sdst + 2048]);                               \
} while (0)

    GSTAGE(0, 0);
    int cur = 0;

    for (int k0 = 0; k0 < K; k0 += 32) {
        __syncthreads();               // drains stage(cur) writes + prev reads
        if (k0 + 32 < K) GSTAGE(cur ^ 1, k0 + 32);

        short8 af[4], bf[4];
#pragma unroll
        for (int mt = 0; mt < 4; mt++) af[mt] = *(const short8*)&As[cur][ra + mt * 512];
#pragma unroll
        for (int nt = 0; nt < 4; nt++) bf[nt] = *(const short8*)&Bs[cur][rb + nt * 512];
#pragma unroll
        for (int mt = 0; mt < 4; mt++)
#pragma unroll
            for (int nt = 0; nt < 4; nt++)
                acc[mt][nt] = __builtin_amdgcn_mfma_f32_16x16x32_bf16(
                    af[mt], bf[nt], acc[mt][nt], 0, 0, 0);
        cur ^= 1;
    }
#undef GSTAGE

#pragma unroll
    for (int mt = 0; mt < 4; mt++) {
        int mg = m0 + wr * 64 + mt * 16 + (lane >> 4) * 4;
#pragma unroll
        for (int nt = 0; nt < 4; nt++) {
            int ng = n0 + wc * 64 + nt * 16 + (lane & 15);
#pragma unroll
            for (int r = 0; r < 4; r++) {
                float v = acc[mt][nt][r];
                if (BIAS_MODE == 1) v += bias[mg + r];
                if (BIAS_MODE == 2) v += bias[ng];
                if (OUT_BF16) {
                    u16* D = (u16*)Dv + (size_t)z * batchD;
                    D[(size_t)(mg + r) * ldd + ng] = f2b(v);
                } else {
                    float* D = (float*)Dv + (size_t)z * batchD;
                    D[(size_t)(mg + r) * ldd + ng] = v;
                }
            }
        }
    }
}

// ---------------------------------------------------------------------------
// Flash attention, 32x32 swapped-operand structure (j-quarters), jtile=32,
// double-buffered staging, defer-max (round-10 schedule):
//   [barrier] STAGE(next) | QKT (2 indep 8-chains) | softmax (raw exp2) | PV
// Block: 128 q x one K/V quarter. grid 512 = 4n x 4jh x 32qt; 2 blocks/CU.
// Round-17: QKT split into svx+svy (breaks the 16-deep dependent-MFMA chain);
// V fragments batch-loaded (8x ds_read_b128) before each PV MFMA run.
// VGPR headroom is free: occupancy is LDS-capped (2 x 64 KB), cap 256 regs.
// ---------------------------------------------------------------------------
__global__ __launch_bounds__(256, 2)
void flash_attn(const u16* __restrict__ THPH, const u16* __restrict__ G,
                u16* __restrict__ OPB, unsigned* __restrict__ ML4) {
    __shared__ __align__(16) u16 Ks[2][32 * 256];   // 2 x 16 KB
    __shared__ __align__(16) u16 Vs[2][256 * 32];   // 2 x 16 KB

    int b = blockIdx.x;
    int n = b & 3;
    int jh = (b >> 2) & 3;         // K/V quarter
    int qt = b >> 4;               // 0..31
    int q0 = qt * 128;

    const u16* TH = THPH + (size_t)n * LDIM * 512;
    const u16* PH = TH + 256;
    const u16* Gn = G + (size_t)n * LDIM * CIDIM;
    u16* OPh = OPB + ((size_t)jh * NB + n) * CIDIM * LDIM;
    unsigned* MLh = ML4 + ((size_t)jh * NB + n) * LDIM;

    int tid = threadIdx.x, lane = tid & 63, w = tid >> 6;
    int h = lane >> 5, lq = lane & 31, l7 = lane & 7;

    // ---- Q fragments (B-operand): qf[c] = Q[q0+w*32+lq][c*16 + h*8 .. +7] ----
    short8 qf[16];
    {
        const u16* qb = TH + (size_t)(q0 + w * 32 + lq) * 512 + h * 8;
#pragma unroll
        for (int c = 0; c < 16; c++) qf[c] = *(const short8*)(qb + c * 16);
    }

    f32x16 o[8];
#pragma unroll
    for (int i = 0; i < 8; i++)
#pragma unroll
        for (int e = 0; e < 16; e++) o[i][e] = 0.f;
    float m = -3e38f, lsum = 0.f;

    // staging decompositions
    int krh = lane >> 5;                      // K: row sub-offset (0/1)
    int ksl = lane & 31;                      // K: phys 16B slot
    int vr = lane >> 2;                       // V: row sub-offset (0..15)
    int vsl = (lane & 3) ^ ((lane >> 3) & 3); // V: swizzled source slot ((r>>1)&3)

    // K tile: 16 KB, 4 issues/wave x 2 rows; rows w*8 .. w*8+7
    // V tile: 16 KB, 4 issues/wave x 16 rows; rows w*64 .. w*64+63
#define STAGE(bufi, jt_) do {                                                  \
    int j0_ = jh * 1024 + (jt_) * 32;                                          \
    _Pragma("unroll")                                                          \
    for (int i = 0; i < 4; i++) {                                              \
        int r = w * 8 + 2 * i + krh;                                           \
        int s = ksl ^ (r & 7);                                                 \
        gl_lds16(PH + (size_t)(j0_ + r) * 512 + s * 8,                         \
                 &Ks[bufi][(w * 8 + 2 * i) * 256]);                            \
    }                                                                          \
    _Pragma("unroll")                                                          \
    for (int i = 0; i < 4; i++) {                                              \
        int r = w * 64 + 16 * i + vr;                                          \
        gl_lds16(Gn + (size_t)r * LDIM + j0_ + vsl * 8,                        \
                 &Vs[bufi][(w * 64 + 16 * i) * 32]);                           \
    }                                                                          \
} while (0)

    STAGE(0, 0);
    int cur = 0;

#pragma unroll 1
    for (int jt = 0; jt < 32; jt++) {
        __syncthreads();               // drains buf[cur] writes + prev reads
        if (jt + 1 < 32) STAGE(cur ^ 1, jt + 1);   // prefetch next tile

        const u16* kb = Ks[cur];
        const u16* vb = Vs[cur];

        // ---- S^T = K Q^T : two independent 8-step chains ----
        f32x16 svx, svy;
#pragma unroll
        for (int e = 0; e < 16; e++) { svx[e] = 0.f; svy[e] = 0.f; }
#pragma unroll
        for (int c = 0; c < 8; c++) {
            int slot = (c * 2 + h) ^ l7;
            short8 ka = *(const short8*)&kb[lq * 256 + slot * 8];
            svx = __builtin_amdgcn_mfma_f32_32x32x16_bf16(ka, qf[c], svx, 0, 0, 0);
        }
#pragma unroll
        for (int c = 8; c < 16; c++) {
            int slot = (c * 2 + h) ^ l7;
            short8 ka = *(const short8*)&kb[lq * 256 + slot * 8];
            svy = __builtin_amdgcn_mfma_f32_32x32x16_bf16(ka, qf[c], svy, 0, 0, 0);
        }
        f32x16 sv = svx + svy;

        // ---- online softmax (defer-max; lane-local, q = l&31; log2 space) ----
        float tm = sv[0];
#pragma unroll
        for (int r = 1; r < 16; r++) tm = fmaxf(tm, sv[r]);
        tm = fmaxf(tm, __shfl_xor(tm, 32, 64));

        if (!__all(tm <= m + 11.5f)) {
            float mnew = fmaxf(m, tm);
            float al = fast_exp2(m - mnew);
            m = mnew;
            lsum *= al;
#pragma unroll
            for (int i = 0; i < 8; i++)
#pragma unroll
                for (int e = 0; e < 16; e++) o[i][e] *= al;
        }

        float rs = 0.f;
#pragma unroll
        for (int r = 0; r < 16; r++) {
            float p = fast_exp2(sv[r] - m);
            sv[r] = p;
            rs += p;
        }
        lsum += rs + __shfl_xor(rs, 32, 64);

        // ---- PV: O^T[ci][q] += V[ci][j] * P[j][q], 2 j-steps of 16 ----
        // B-frag step st: u[0],u[1] = P(r=8*st+4*0+0..3), u[2],u[3] =
        // P(r=8*st+4*1+0..3); own half supplies hp=h, shfl_xor(32) the other.
#pragma unroll
        for (int st = 0; st < 2; st++) {
            int r0 = 8 * st;
            float e0 = sv[r0 + 0], e1 = sv[r0 + 1];
            float e2 = sv[r0 + 2], e3 = sv[r0 + 3];
            float e4 = sv[r0 + 4], e5 = sv[r0 + 5];
            float e6 = sv[r0 + 6], e7 = sv[r0 + 7];
            unsigned own_a = h ? pack2(e4, e5) : pack2(e0, e1);
            unsigned own_b = h ? pack2(e6, e7) : pack2(e2, e3);
            unsigned snd_a = h ? pack2(e0, e1) : pack2(e4, e5);
            unsigned snd_b = h ? pack2(e2, e3) : pack2(e6, e7);
            unsigned rcv_a = __shfl_xor(snd_a, 32, 64);
            unsigned rcv_b = __shfl_xor(snd_b, 32, 64);
            union { unsigned u[4]; short8 v; } pf;
            pf.u[0] = h ? rcv_a : own_a;   // hp=0 source
            pf.u[1] = h ? rcv_b : own_b;
            pf.u[2] = h ? own_a : rcv_a;   // hp=1 source
            pf.u[3] = h ? own_b : rcv_b;
            int slot = (st * 2 + h) ^ ((lq >> 1) & 3);
            short8 va[8];
#pragma unroll
            for (int cit = 0; cit < 8; cit++)
                va[cit] = *(const short8*)&vb[(cit * 32 + lq) * 32 + slot * 8];
#pragma unroll
            for (int cit = 0; cit < 8; cit++)
                o[cit] = __builtin_amdgcn_mfma_f32_32x32x16_bf16(va[cit], pf.v, o[cit], 0, 0, 0);
        }
        cur ^= 1;
    }

    // ---- epilogue: bf16 partial O^T (ci, q); per-q (m, l) packed half2 ----
    int q = q0 + w * 32 + lq;
    if (h == 0) {
        unsigned pm = (unsigned)__half_as_ushort(__float2half(m));
        unsigned pl = (unsigned)__half_as_ushort(__float2half(lsum));
        MLh[q] = pm | (pl << 16);
    }
#pragma unroll
    for (int cit = 0; cit < 8; cit++)
#pragma unroll
        for (int rr = 0; rr < 16; rr++) {
            int ci = cit * 32 + (rr & 3) + 8 * (rr >> 2) + 4 * h;
            OPh[(size_t)ci * LDIM + q] = f2b(o[cit][rr]);
        }
#undef STAGE
}

// ---------------------------------------------------------------------------
// Merge the four j-quarters + transpose: OPB quarters are (n, ci, l) bf16;
// Y output is (n, l, ci) bf16. 32x32 tiles, threads (32, 8).
// (m is in log2 space -> raw exp2.)
// ---------------------------------------------------------------------------
__global__ void merge_y(const u16* __restrict__ OPB, const unsigned* __restrict__ ML4,
                        u16* __restrict__ Y) {
    __shared__ u16 tile[32][33];
    int nn = blockIdx.z;
    int l0 = blockIdx.x * 32, ci0 = blockIdx.y * 32;
    int tx = threadIdx.x, ty = threadIdx.y;
    int l = l0 + tx;

    float mq[4], lq[4];
#pragma unroll
    for (int q = 0; q < 4; q++) {
        unsigned u = ML4[((size_t)q * NB + nn) * LDIM + l];
        mq[q] = __half2float(__ushort_as_half((unsigned short)(u & 0xffff)));
        lq[q] = __half2float(__ushort_as_half((unsigned short)(u >> 16)));
    }
    float M = fmaxf(fmaxf(mq[0], mq[1]), fmaxf(mq[2], mq[3]));
    float wq[4];
    float den = 0.f;
#pragma unroll
    for (int q = 0; q < 4; q++) {
        wq[q] = fast_exp2(mq[q] - M);
        den += lq[q] * wq[q];
    }
    float inv = 1.f / den;
#pragma unroll
    for (int q = 0; q < 4; q++) wq[q] *= inv;

#pragma unroll
    for (int k = 0; k < 4; k++) {
        int ci = ci0 + ty + 8 * k;
        float acc = 0.f;
#pragma unroll
        for (int q = 0; q < 4; q++)
            acc += b2f(OPB[((size_t)q * NB + nn) * CIDIM * LDIM + (size_t)ci * LDIM + l]) * wq[q];
        tile[ty + 8 * k][tx] = f2b(acc);
    }
    __syncthreads();
    u16* Yn = Y + (size_t)nn * LDIM * CIDIM;
#pragma unroll
    for (int k = 0; k < 4; k++)
        Yn[(size_t)(l0 + ty + 8 * k) * CIDIM + ci0 + tx] = tile[tx][ty + 8 * k];
}

// ---------------------------------------------------------------------------
// BN stats per channel o over (N, L). WY layout (N, C, L) fp32.
// ---------------------------------------------------------------------------
__global__ void bn_stats_kernel(const float* __restrict__ WY, float* __restrict__ stats) {
    int o = blockIdx.x, tid = threadIdx.x, lane = tid & 63, wave = tid >> 6;
    float s = 0.f, s2 = 0.f;
    for (int n = 0; n < NB; n++) {
        const float4* p = (const float4*)(WY + (size_t)(n * CDIM + o) * LDIM);
        for (int i = tid; i < LDIM / 4; i += 256) {
            float4 v = p[i];
            s += v.x + v.y + v.z + v.w;
            s2 += v.x * v.x + v.y * v.y + v.z * v.z + v.w * v.w;
        }
    }
    for (int o2 = 32; o2 > 0; o2 >>= 1) {
        s += __shfl_xor(s, o2, 64);
        s2 += __shfl_xor(s2, o2, 64);
    }
    __shared__ float rs[4], rs2[4];
    if (lane == 0) { rs[wave] = s; rs2[wave] = s2; }
    __syncthreads();
    if (tid == 0) {
        float S = rs[0] + rs[1] + rs[2] + rs[3];
        float S2 = rs2[0] + rs2[1] + rs2[2] + rs2[3];
        const float cnt = (float)(NB * LDIM);
        float mean = S / cnt;
        float var = S2 / cnt - mean * mean;
        stats[o] = mean;
        stats[CDIM + o] = rsqrtf(var + BN_EPS);
    }
}

// ---------------------------------------------------------------------------
// BN apply + residual, float4 vectorized.
// ---------------------------------------------------------------------------
__global__ void bn_apply_kernel(const float* __restrict__ WY, const float* __restrict__ stats,
                                const float* __restrict__ x,
                                const float* __restrict__ gamma, const float* __restrict__ beta,
                                float* __restrict__ out) {
    int i4 = blockIdx.x * 256 + threadIdx.x;  // < N*C*L/4
    int o = (i4 >> 10) & (CDIM - 1);
    float m = stats[o], is = stats[CDIM + o];
    float ga = gamma[o], be = beta[o];
    float4 w = ((const float4*)WY)[i4];
    float4 xv = ((const float4*)x)[i4];
    float4 r;
    r.x = (w.x - m) * is * ga + be + xv.x;
    r.y = (w.y - m) * is * ga + be + xv.y;
    r.z = (w.z - m) * is * ga + be + xv.z;
    r.w = (w.w - m) * is * ga + be + xv.w;
    ((float4*)out)[i4] = r;
}

// ---------------------------------------------------------------------------
extern "C" void kernel_launch(void* const* d_in, const int* in_sizes, int n_in,
                              void* d_out, int out_size, void* d_ws, size_t ws_size,
                              hipStream_t stream) {
    const float* x   = (const float*)d_in[0];
    const float* gw  = (const float*)d_in[1];
    const float* gb  = (const float*)d_in[2];
    const float* tw  = (const float*)d_in[3];
    const float* tb  = (const float*)d_in[4];
    const float* pw  = (const float*)d_in[5];
    const float* pb  = (const float*)d_in[6];
    const float* zw  = (const float*)d_in[7];
    const float* zb  = (const float*)d_in[8];
    const float* bng = (const float*)d_in[9];
    const float* bnb = (const float*)d_in[10];
    float* out = (float*)d_out;
    float* ws  = (float*)d_ws;

    float*    WY   = ws + WY_OFF;
    u16*      xT   = (u16*)(ws + WY_OFF);    // dies before flash writes OPB
    u16*      OPB  = (u16*)(ws + WY_OFF);    // bf16 partials; die before WY
    u16*      THPH = (u16*)(ws + THPH_OFF);  // (N, L, 512) = [theta | phi]
    u16*      G    = (u16*)(ws + G_OFF);     // (N, CI, L)
    u16*      Y    = (u16*)(ws + Y_OFF);     // (N, L, CI)
    u16*      WB   = (u16*)(ws + WTS_OFF);   // [gw | tw | pw | zw] bf16
    float*    BC   = ws + BIAS2_OFF;         // [tb*log2e | pb]
    unsigned* ML4  = (unsigned*)(ws + ML_OFF);
    float*    ST   = ws + ST_OFF;

    const long LC   = (long)LDIM * CDIM;    // xT batch (u16)
    const long LCI  = (long)LDIM * CIDIM;
    const long L512 = (long)LDIM * 512;     // THPH batch (u16)
    const long CL   = (long)CDIM * LDIM;    // WY batch (fp32)

    transpose_x<<<dim3(LDIM / 32, CDIM / 32, NB), dim3(32, 8), 0, stream>>>(x, xT);
    cast_w<<<2050, 256, 0, stream>>>(gw, tw, pw, zw, WB, tb, pb, BC);

    // THPH (N,L,512) = xT(L,C) x [tw;pw](512,C)^T   [bias per-n = BC]
    gemm_nt<2, true><<<dim3(4, 32, NB), 256, 0, stream>>>(
        xT, WB + 131072, THPH, BC, CDIM, CDIM, CDIM, 512, LC, 0, L512);
    // g (N,CI,L) = gw(CI,C) x xT(L,C)^T             [bias per-m]
    gemm_nt<1, true><<<dim3(32, 2, NB), 256, 0, stream>>>(
        WB, xT, G, gb, CDIM, CDIM, CDIM, LDIM, 0, LC, LCI);

    // fused attention (j-quarters x4) + merge-transpose
    flash_attn<<<dim3(512), 256, 0, stream>>>(THPH, G, OPB, ML4);
    merge_y<<<dim3(LDIM / 32, CIDIM / 32, NB), dim3(32, 8), 0, stream>>>(OPB, ML4, Y);

    // WY (N,C,L) fp32 = zw(C,CI) x yT(L,CI)^T  [bias per-m]
    gemm_nt<1, false><<<dim3(32, 4, NB), 256, 0, stream>>>(
        WB + 393216, Y, (void*)WY, zb, CIDIM, CIDIM, CIDIM, LDIM, 0, LCI, CL);

    bn_stats_kernel<<<dim3(CDIM), 256, 0, stream>>>(WY, ST);
    bn_apply_kernel<<<dim3(NB * CDIM * LDIM / 4 / 256), 256, 0, stream>>>(
        WY, ST, x, bng, bnb, out);
}

// Round 11
// 275.679 us; speedup vs baseline: 1.0886x; 1.0886x over previous
//
#include <hip/hip_runtime.h>
#include <hip/hip_bf16.h>
#include <hip/hip_fp16.h>

// NLBlockND (embedded non-local block), MI355X/gfx950.
// Round 18: (a) flash = EXACT round-16 revert (verified 107.6 us). Round-17's
// svx/svy + va[8] spilled: launch_bounds(256,2) caps the unified reg file at
// 256/wave and o[8](128 AGPR)+qf(64) already sit at the ceiling — FETCH/WRITE
// +11.5 MB scratch proved it. LESSON (3rd time): no added live ranges in flash.
// (b) keep round-17 gemm dbuf (non-flash 173->167.7). (c) NEW, register-
// isolated: bn_stats fused into the wz-GEMM epilogue (LDS reduce + atomics
// into ST sums; bn_finalize converts to mean/rsqrt; ST zeroed in cast_w tail).
// Removes a 33.5 MB read pass + one launch.
// Kept lessons: raw v_exp_f32 (exp2f = precise libm), no setprio (m190),
// sequential reductions, thr 11.5 log2 = 8 nats.
// Shapes: N=4, C=512, CI=256, L=4096.

#define NB    4
#define CDIM  512
#define CIDIM 256
#define LDIM  4096
#define BN_EPS 1e-5f
#define LOG2E 1.4426950408889634f

typedef unsigned short u16;
typedef __attribute__((ext_vector_type(8))) short short8;    // 8 bf16 (4 VGPRs)
typedef __attribute__((ext_vector_type(4))) float f32x4;     // 16x16 MFMA C/D
typedef __attribute__((ext_vector_type(16))) float f32x16;   // 32x32 MFMA C/D

// Workspace (float offsets). WY region hosts, in sequence: xT (bf16, dies
// after projections) -> OPB partials (bf16, die after merge) -> WY (fp32).
#define WY_OFF    0                  // 8,388,608 floats
#define THPH_OFF  8388608            // 4,194,304 floats (N,L,512 bf16 [theta|phi])
#define G_OFF     12582912           // 2,097,152 floats (g bf16, (N,CI,L))
#define Y_OFF     14680064           // 2,097,152 floats (yT bf16, (N,L,CI))
#define WTS_OFF   16777216           //   262,144 floats = 524,288 bf16 weights
#define BIAS2_OFF 17039360           //       512 floats ([tb|pb])
#define ML_OFF    17039872           //    65,536 floats (4 quarters x N*L half2)
#define ST_OFF    17105408           //     1,024 floats ([sums C] [sumsq C] -> [mean][rsqrt])
// total 17,106,432 floats = 68.4 MB (unchanged)

__device__ __forceinline__ u16 f2b(float f) {  // fp32 -> bf16 RNE
    union { float f; unsigned u; } v; v.f = f;
    return (u16)((v.u + 0x7FFFu + ((v.u >> 16) & 1u)) >> 16);
}

__device__ __forceinline__ float b2f(u16 x) {
    return __uint_as_float((unsigned)x << 16);
}

__device__ __forceinline__ unsigned pack2(float a, float b) {
    return (unsigned)f2b(a) | ((unsigned)f2b(b) << 16);
}

// raw hardware exp2: one v_exp_f32, no denormal fixup (fine for softmax P)
__device__ __forceinline__ float fast_exp2(float x) {
#if __has_builtin(__builtin_amdgcn_exp2f)
    return __builtin_amdgcn_exp2f(x);
#else
    float r; asm("v_exp_f32 %0, %1" : "=v"(r) : "v"(x)); return r;
#endif
}

__device__ __forceinline__ void gl_lds16(const u16* g, u16* l) {
    __builtin_amdgcn_global_load_lds(
        (const __attribute__((address_space(1))) void*)g,
        (__attribute__((address_space(3))) void*)l, 16, 0, 0);
}

// ---------------------------------------------------------------------------
// x (N,C,L) fp32 -> xT (N,L,C) bf16.  32x32 LDS tiles.
// ---------------------------------------------------------------------------
__global__ void transpose_x(const float* __restrict__ x, u16* __restrict__ xt) {
    __shared__ float tile[32][33];
    int n = blockIdx.z;
    int l0 = blockIdx.x * 32, c0 = blockIdx.y * 32;
    const float* xn = x + (size_t)n * CDIM * LDIM;
    u16* xtn = xt + (size_t)n * LDIM * CDIM;
    int tx = threadIdx.x, ty = threadIdx.y;  // (32, 8)
#pragma unroll
    for (int k = 0; k < 4; k++)
        tile[ty + 8 * k][tx] = xn[(size_t)(c0 + ty + 8 * k) * LDIM + l0 + tx];
    __syncthreads();
#pragma unroll
    for (int k = 0; k < 4; k++)
        xtn[(size_t)(l0 + ty + 8 * k) * CDIM + c0 + tx] = f2b(tile[tx][ty + 8 * k]);
}

// ---------------------------------------------------------------------------
// Cast the 4 weight matrices (each 131072 fp32) to bf16, concatenated;
// theta (seg 1) pre-scaled by log2(e) so flash softmax uses exp2 directly.
// Tail blocks also build [tb*log2e | pb] and ZERO the ST sums region.
// ---------------------------------------------------------------------------
__global__ void cast_w(const float* __restrict__ gw, const float* __restrict__ tw,
                       const float* __restrict__ pw, const float* __restrict__ zw,
                       u16* __restrict__ out,
                       const float* __restrict__ tb, const float* __restrict__ pb,
                       float* __restrict__ bc, float* __restrict__ st) {
    int idx = blockIdx.x * 256 + threadIdx.x;
    if (idx < 4 * 131072) {
        int seg = idx >> 17, off = idx & 131071;
        const float* s = (seg == 0) ? gw : (seg == 1) ? tw : (seg == 2) ? pw : zw;
        float v = s[off];
        if (seg == 1) v *= LOG2E;
        out[idx] = f2b(v);
    } else {
        int i = idx - 4 * 131072;
        if (i < 256) bc[i] = tb[i] * LOG2E;
        else if (i < 512) bc[i] = pb[i - 256];
        else if (i < 1536) st[i - 512] = 0.f;
    }
}

// ---------------------------------------------------------------------------
// NT-GEMM: D[m][n] = sum_k A[m][k]*B[n][k] (+bias). 128x128 tile, BK=32,
// 256 threads (4 waves 2x2), 16x16x32 bf16 MFMA, double-buffered
// global_load_lds staging (one barrier per k-step), slot^row&3 swizzle.
// FUSE_STATS: epilogue accumulates per-channel sum/sumsq (over the n-dim)
// into stats[] via LDS reduce + global atomics (for the BN over WY).
// ---------------------------------------------------------------------------
template <int BIAS_MODE, bool OUT_BF16, bool FUSE_STATS>
__global__ __launch_bounds__(256)
void gemm_nt(const u16* __restrict__ A, const u16* __restrict__ B,
             void* __restrict__ Dv, const float* __restrict__ bias,
             float* __restrict__ stats,
             int K, int lda, int ldb, int ldd,
             long batchA, long batchB, long batchD) {
    __shared__ __align__(16) u16 As[2][128 * 32];
    __shared__ __align__(16) u16 Bs[2][128 * 32];
    __shared__ float sred[256];            // FUSE_STATS reduction ([s|s2] x 128)
    int z = blockIdx.z;
    A += (size_t)z * batchA;
    B += (size_t)z * batchB;

    int tid = threadIdx.x, lane = tid & 63, wave = tid >> 6;
    int n0 = blockIdx.x * 128, m0 = blockIdx.y * 128;
    int wr = wave >> 1, wc = wave & 1;

    f32x4 acc[4][4];
#pragma unroll
    for (int i = 0; i < 4; i++)
#pragma unroll
        for (int j = 0; j < 4; j++) acc[i][j] = (f32x4){0.f, 0.f, 0.f, 0.f};

    int sr = wave * 16 + (lane >> 2);
    int ss = ((lane & 3) ^ ((lane >> 2) & 3)) * 8;
    const u16* Ag0 = A + (size_t)(m0 + sr) * lda + ss;
    const u16* Ag1 = A + (size_t)(m0 + 64 + sr) * lda + ss;
    const u16* Bg0 = B + (size_t)(n0 + sr) * ldb + ss;
    const u16* Bg1 = B + (size_t)(n0 + 64 + sr) * ldb + ss;
    int sdst = wave * 16 * 32;           // wave's quarter; +2048 = +64 rows

    int koff = ((lane >> 4) ^ (lane & 3)) * 8;
    int ra = (wr * 64 + (lane & 15)) * 32 + koff;
    int rb = (wc * 64 + (lane & 15)) * 32 + koff;

#define GSTAGE(bi, k0_) do {                                                   \
    gl_lds16(Ag0 + (k0_), &As[bi][sdst]);                                      \
    gl_lds16(Ag1 + (k0_), &As[bi][sdst + 2048]);                               \
    gl_lds16(Bg0 + (k0_), &Bs[bi][sdst]);                                      \
    gl_lds16(Bg1 + (k0_), &Bs[bi][sdst + 2048]);                               \
} while (0)

    GSTAGE(0, 0);
    int cur = 0;

    for (int k0 = 0; k0 < K; k0 += 32) {
        __syncthreads();               // drains stage(cur) writes + prev reads
        if (k0 + 32 < K) GSTAGE(cur ^ 1, k0 + 32);

        short8 af[4], bf[4];
#pragma unroll
        for (int mt = 0; mt < 4; mt++) af[mt] = *(const short8*)&As[cur][ra + mt * 512];
#pragma unroll
        for (int nt = 0; nt < 4; nt++) bf[nt] = *(const short8*)&Bs[cur][rb + nt * 512];
#pragma unroll
        for (int mt = 0; mt < 4; mt++)
#pragma unroll
            for (int nt = 0; nt < 4; nt++)
                acc[mt][nt] = __builtin_amdgcn_mfma_f32_16x16x32_bf16(
                    af[mt], bf[nt], acc[mt][nt], 0, 0, 0);
        cur ^= 1;
    }
#undef GSTAGE

    if (FUSE_STATS) {
        sred[tid] = 0.f;
        __syncthreads();
    }

#pragma unroll
    for (int mt = 0; mt < 4; mt++) {
        int mg = m0 + wr * 64 + mt * 16 + (lane >> 4) * 4;
        float ls[4] = {0.f, 0.f, 0.f, 0.f}, ls2[4] = {0.f, 0.f, 0.f, 0.f};
#pragma unroll
        for (int nt = 0; nt < 4; nt++) {
            int ng = n0 + wc * 64 + nt * 16 + (lane & 15);
#pragma unroll
            for (int r = 0; r < 4; r++) {
                float v = acc[mt][nt][r];
                if (BIAS_MODE == 1) v += bias[mg + r];
                if (BIAS_MODE == 2) v += bias[ng];
                if (OUT_BF16) {
                    u16* D = (u16*)Dv + (size_t)z * batchD;
                    D[(size_t)(mg + r) * ldd + ng] = f2b(v);
                } else {
                    float* D = (float*)Dv + (size_t)z * batchD;
                    D[(size_t)(mg + r) * ldd + ng] = v;
                }
                if (FUSE_STATS) { ls[r] += v; ls2[r] += v * v; }
            }
        }
        if (FUSE_STATS) {
#pragma unroll
            for (int r = 0; r < 4; r++) {
                float s = ls[r], s2 = ls2[r];
#pragma unroll
                for (int msk = 1; msk <= 8; msk <<= 1) {
                    s += __shfl_xor(s, msk, 64);
                    s2 += __shfl_xor(s2, msk, 64);
                }
                if ((lane & 15) == 0) {
                    int ch = wr * 64 + mt * 16 + (lane >> 4) * 4 + r;  // 0..127
                    atomicAdd(&sred[ch], s);
                    atomicAdd(&sred[128 + ch], s2);
                }
            }
        }
    }

    if (FUSE_STATS) {
        __syncthreads();
        if (tid < 128) {
            atomicAdd(&stats[m0 + tid], sred[tid]);
            atomicAdd(&stats[CDIM + m0 + tid], sred[128 + tid]);
        }
    }
}

// ---------------------------------------------------------------------------
// Convert ST sums -> [mean | rsqrt(var+eps)] in place.
// ---------------------------------------------------------------------------
__global__ void bn_finalize(float* __restrict__ stats) {
    int o = blockIdx.x * 256 + threadIdx.x;
    if (o >= CDIM) return;
    const float cnt = (float)(NB * LDIM);
    float mean = stats[o] / cnt;
    float var = stats[CDIM + o] / cnt - mean * mean;
    stats[o] = mean;
    stats[CDIM + o] = rsqrtf(var + BN_EPS);
}

// ---------------------------------------------------------------------------
// Flash attention, 32x32 swapped-operand structure (j-quarters), jtile=32,
// double-buffered staging, defer-max (round-16 EXACT, verified 107.6 us):
//   [barrier] STAGE(next) | QKT | softmax (raw exp2, sequential) | PV
// Block: 128 q x one K/V quarter. grid 512 = 4n x 4jh x 32qt; 2 blocks/CU.
// NO setprio. NO extra live ranges (unified reg file is at the 256 ceiling).
// ---------------------------------------------------------------------------
__global__ __launch_bounds__(256, 2)
void flash_attn(const u16* __restrict__ THPH, const u16* __restrict__ G,
                u16* __restrict__ OPB, unsigned* __restrict__ ML4) {
    __shared__ __align__(16) u16 Ks[2][32 * 256];   // 2 x 16 KB
    __shared__ __align__(16) u16 Vs[2][256 * 32];   // 2 x 16 KB

    int b = blockIdx.x;
    int n = b & 3;
    int jh = (b >> 2) & 3;         // K/V quarter
    int qt = b >> 4;               // 0..31
    int q0 = qt * 128;

    const u16* TH = THPH + (size_t)n * LDIM * 512;
    const u16* PH = TH + 256;
    const u16* Gn = G + (size_t)n * LDIM * CIDIM;
    u16* OPh = OPB + ((size_t)jh * NB + n) * CIDIM * LDIM;
    unsigned* MLh = ML4 + ((size_t)jh * NB + n) * LDIM;

    int tid = threadIdx.x, lane = tid & 63, w = tid >> 6;
    int h = lane >> 5, lq = lane & 31, l7 = lane & 7;

    // ---- Q fragments (B-operand): qf[c] = Q[q0+w*32+lq][c*16 + h*8 .. +7] ----
    short8 qf[16];
    {
        const u16* qb = TH + (size_t)(q0 + w * 32 + lq) * 512 + h * 8;
#pragma unroll
        for (int c = 0; c < 16; c++) qf[c] = *(const short8*)(qb + c * 16);
    }

    f32x16 o[8];
#pragma unroll
    for (int i = 0; i < 8; i++)
#pragma unroll
        for (int e = 0; e < 16; e++) o[i][e] = 0.f;
    float m = -3e38f, lsum = 0.f;

    // staging decompositions
    int krh = lane >> 5;                      // K: row sub-offset (0/1)
    int ksl = lane & 31;                      // K: phys 16B slot
    int vr = lane >> 2;                       // V: row sub-offset (0..15)
    int vsl = (lane & 3) ^ ((lane >> 3) & 3); // V: swizzled source slot ((r>>1)&3)

    // K tile: 16 KB, 4 issues/wave x 2 rows; rows w*8 .. w*8+7
    // V tile: 16 KB, 4 issues/wave x 16 rows; rows w*64 .. w*64+63
#define STAGE(bufi, jt_) do {                                                  \
    int j0_ = jh * 1024 + (jt_) * 32;                                          \
    _Pragma("unroll")                                                          \
    for (int i = 0; i < 4; i++) {                                              \
        int r = w * 8 + 2 * i + krh;                                           \
        int s = ksl ^ (r & 7);                                                 \
        gl_lds16(PH + (size_t)(j0_ + r) * 512 + s * 8,                         \
                 &Ks[bufi][(w * 8 + 2 * i) * 256]);                            \
    }                                                                          \
    _Pragma("unroll")                                                          \
    for (int i = 0; i < 4; i++) {                                              \
        int r = w * 64 + 16 * i + vr;                                          \
        gl_lds16(Gn + (size_t)r * LDIM + j0_ + vsl * 8,                        \
                 &Vs[bufi][(w * 64 + 16 * i) * 32]);                           \
    }                                                                          \
} while (0)

    STAGE(0, 0);
    int cur = 0;

#pragma unroll 1
    for (int jt = 0; jt < 32; jt++) {
        __syncthreads();               // drains buf[cur] writes + prev reads
        if (jt + 1 < 32) STAGE(cur ^ 1, jt + 1);   // prefetch next tile

        const u16* kb = Ks[cur];
        const u16* vb = Vs[cur];

        // ---- S^T = K Q^T : 16 ci-steps ----
        f32x16 sv;
#pragma unroll
        for (int e = 0; e < 16; e++) sv[e] = 0.f;
#pragma unroll
        for (int c = 0; c < 16; c++) {
            int slot = (c * 2 + h) ^ l7;
            short8 ka = *(const short8*)&kb[lq * 256 + slot * 8];
            sv = __builtin_amdgcn_mfma_f32_32x32x16_bf16(ka, qf[c], sv, 0, 0, 0);
        }

        // ---- online softmax (defer-max; lane-local, q = l&31; log2 space) ----
        float tm = sv[0];
#pragma unroll
        for (int r = 1; r < 16; r++) tm = fmaxf(tm, sv[r]);
        tm = fmaxf(tm, __shfl_xor(tm, 32, 64));

        if (!__all(tm <= m + 11.5f)) {
            float mnew = fmaxf(m, tm);
            float al = fast_exp2(m - mnew);
            m = mnew;
            lsum *= al;
#pragma unroll
            for (int i = 0; i < 8; i++)
#pragma unroll
                for (int e = 0; e < 16; e++) o[i][e] *= al;
        }

        float rs = 0.f;
#pragma unroll
        for (int r = 0; r < 16; r++) {
            float p = fast_exp2(sv[r] - m);
            sv[r] = p;
            rs += p;
        }
        lsum += rs + __shfl_xor(rs, 32, 64);

        // ---- PV: O^T[ci][q] += V[ci][j] * P[j][q], 2 j-steps of 16 ----
        // B-frag step st: u[0],u[1] = P(r=8*st+4*0+0..3), u[2],u[3] =
        // P(r=8*st+4*1+0..3); own half supplies hp=h, shfl_xor(32) the other.
#pragma unroll
        for (int st = 0; st < 2; st++) {
            int r0 = 8 * st;
            float e0 = sv[r0 + 0], e1 = sv[r0 + 1];
            float e2 = sv[r0 + 2], e3 = sv[r0 + 3];
            float e4 = sv[r0 + 4], e5 = sv[r0 + 5];
            float e6 = sv[r0 + 6], e7 = sv[r0 + 7];
            unsigned own_a = h ? pack2(e4, e5) : pack2(e0, e1);
            unsigned own_b = h ? pack2(e6, e7) : pack2(e2, e3);
            unsigned snd_a = h ? pack2(e0, e1) : pack2(e4, e5);
            unsigned snd_b = h ? pack2(e2, e3) : pack2(e6, e7);
            unsigned rcv_a = __shfl_xor(snd_a, 32, 64);
            unsigned rcv_b = __shfl_xor(snd_b, 32, 64);
            union { unsigned u[4]; short8 v; } pf;
            pf.u[0] = h ? rcv_a : own_a;   // hp=0 source
            pf.u[1] = h ? rcv_b : own_b;
            pf.u[2] = h ? own_a : rcv_a;   // hp=1 source
            pf.u[3] = h ? own_b : rcv_b;
            int slot = (st * 2 + h) ^ ((lq >> 1) & 3);
#pragma unroll
            for (int cit = 0; cit < 8; cit++) {
                short8 va = *(const short8*)&vb[(cit * 32 + lq) * 32 + slot * 8];
                o[cit] = __builtin_amdgcn_mfma_f32_32x32x16_bf16(va, pf.v, o[cit], 0, 0, 0);
            }
        }
        cur ^= 1;
    }

    // ---- epilogue: bf16 partial O^T (ci, q); per-q (m, l) packed half2 ----
    int q = q0 + w * 32 + lq;
    if (h == 0) {
        unsigned pm = (unsigned)__half_as_ushort(__float2half(m));
        unsigned pl = (unsigned)__half_as_ushort(__float2half(lsum));
        MLh[q] = pm | (pl << 16);
    }
#pragma unroll
    for (int cit = 0; cit < 8; cit++)
#pragma unroll
        for (int rr = 0; rr < 16; rr++) {
            int ci = cit * 32 + (rr & 3) + 8 * (rr >> 2) + 4 * h;
            OPh[(size_t)ci * LDIM + q] = f2b(o[cit][rr]);
        }
#undef STAGE
}

// ---------------------------------------------------------------------------
// Merge the four j-quarters + transpose: OPB quarters are (n, ci, l) bf16;
// Y output is (n, l, ci) bf16. 32x32 tiles, threads (32, 8).
// (m is in log2 space -> raw exp2.)
// ---------------------------------------------------------------------------
__global__ void merge_y(const u16* __restrict__ OPB, const unsigned* __restrict__ ML4,
                        u16* __restrict__ Y) {
    __shared__ u16 tile[32][33];
    int nn = blockIdx.z;
    int l0 = blockIdx.x * 32, ci0 = blockIdx.y * 32;
    int tx = threadIdx.x, ty = threadIdx.y;
    int l = l0 + tx;

    float mq[4], lq[4];
#pragma unroll
    for (int q = 0; q < 4; q++) {
        unsigned u = ML4[((size_t)q * NB + nn) * LDIM + l];
        mq[q] = __half2float(__ushort_as_half((unsigned short)(u & 0xffff)));
        lq[q] = __half2float(__ushort_as_half((unsigned short)(u >> 16)));
    }
    float M = fmaxf(fmaxf(mq[0], mq[1]), fmaxf(mq[2], mq[3]));
    float wq[4];
    float den = 0.f;
#pragma unroll
    for (int q = 0; q < 4; q++) {
        wq[q] = fast_exp2(mq[q] - M);
        den += lq[q] * wq[q];
    }
    float inv = 1.f / den;
#pragma unroll
    for (int q = 0; q < 4; q++) wq[q] *= inv;

#pragma unroll
    for (int k = 0; k < 4; k++) {
        int ci = ci0 + ty + 8 * k;
        float acc = 0.f;
#pragma unroll
        for (int q = 0; q < 4; q++)
            acc += b2f(OPB[((size_t)q * NB + nn) * CIDIM * LDIM + (size_t)ci * LDIM + l]) * wq[q];
        tile[ty + 8 * k][tx] = f2b(acc);
    }
    __syncthreads();
    u16* Yn = Y + (size_t)nn * LDIM * CIDIM;
#pragma unroll
    for (int k = 0; k < 4; k++)
        Yn[(size_t)(l0 + ty + 8 * k) * CIDIM + ci0 + tx] = tile[tx][ty + 8 * k];
}

// ---------------------------------------------------------------------------
// BN apply + residual, float4 vectorized.
// ---------------------------------------------------------------------------
__global__ void bn_apply_kernel(const float* __restrict__ WY, const float* __restrict__ stats,
                                const float* __restrict__ x,
                                const float* __restrict__ gamma, const float* __restrict__ beta,
                                float* __restrict__ out) {
    int i4 = blockIdx.x * 256 + threadIdx.x;  // < N*C*L/4
    int o = (i4 >> 10) & (CDIM - 1);
    float m = stats[o], is = stats[CDIM + o];
    float ga = gamma[o], be = beta[o];
    float4 w = ((const float4*)WY)[i4];
    float4 xv = ((const float4*)x)[i4];
    float4 r;
    r.x = (w.x - m) * is * ga + be + xv.x;
    r.y = (w.y - m) * is * ga + be + xv.y;
    r.z = (w.z - m) * is * ga + be + xv.z;
    r.w = (w.w - m) * is * ga + be + xv.w;
    ((float4*)out)[i4] = r;
}

// ---------------------------------------------------------------------------
extern "C" void kernel_launch(void* const* d_in, const int* in_sizes, int n_in,
                              void* d_out, int out_size, void* d_ws, size_t ws_size,
                              hipStream_t stream) {
    const float* x   = (const float*)d_in[0];
    const float* gw  = (const float*)d_in[1];
    const float* gb  = (const float*)d_in[2];
    const float* tw  = (const float*)d_in[3];
    const float* tb  = (const float*)d_in[4];
    const float* pw  = (const float*)d_in[5];
    const float* pb  = (const float*)d_in[6];
    const float* zw  = (const float*)d_in[7];
    const float* zb  = (const float*)d_in[8];
    const float* bng = (const float*)d_in[9];
    const float* bnb = (const float*)d_in[10];
    float* out = (float*)d_out;
    float* ws  = (float*)d_ws;

    float*    WY   = ws + WY_OFF;
    u16*      xT   = (u16*)(ws + WY_OFF);    // dies before flash writes OPB
    u16*      OPB  = (u16*)(ws + WY_OFF);    // bf16 partials; die before WY
    u16*      THPH = (u16*)(ws + THPH_OFF);  // (N, L, 512) = [theta | phi]
    u16*      G    = (u16*)(ws + G_OFF);     // (N, CI, L)
    u16*      Y    = (u16*)(ws + Y_OFF);     // (N, L, CI)
    u16*      WB   = (u16*)(ws + WTS_OFF);   // [gw | tw | pw | zw] bf16
    float*    BC   = ws + BIAS2_OFF;         // [tb*log2e | pb]
    unsigned* ML4  = (unsigned*)(ws + ML_OFF);
    float*    ST   = ws + ST_OFF;

    const long LC   = (long)LDIM * CDIM;    // xT batch (u16)
    const long LCI  = (long)LDIM * CIDIM;
    const long L512 = (long)LDIM * 512;     // THPH batch (u16)
    const long CL   = (long)CDIM * LDIM;    // WY batch (fp32)

    transpose_x<<<dim3(LDIM / 32, CDIM / 32, NB), dim3(32, 8), 0, stream>>>(x, xT);
    cast_w<<<2054, 256, 0, stream>>>(gw, tw, pw, zw, WB, tb, pb, BC, ST);

    // THPH (N,L,512) = xT(L,C) x [tw;pw](512,C)^T   [bias per-n = BC]
    gemm_nt<2, true, false><<<dim3(4, 32, NB), 256, 0, stream>>>(
        xT, WB + 131072, THPH, BC, nullptr, CDIM, CDIM, CDIM, 512, LC, 0, L512);
    // g (N,CI,L) = gw(CI,C) x xT(L,C)^T             [bias per-m]
    gemm_nt<1, true, false><<<dim3(32, 2, NB), 256, 0, stream>>>(
        WB, xT, G, gb, nullptr, CDIM, CDIM, CDIM, LDIM, 0, LC, LCI);

    // fused attention (j-quarters x4) + merge-transpose
    flash_attn<<<dim3(512), 256, 0, stream>>>(THPH, G, OPB, ML4);
    merge_y<<<dim3(LDIM / 32, CIDIM / 32, NB), dim3(32, 8), 0, stream>>>(OPB, ML4, Y);

    // WY (N,C,L) fp32 = zw(C,CI) x yT(L,CI)^T  [bias per-m] + fused BN sums
    gemm_nt<1, false, true><<<dim3(32, 4, NB), 256, 0, stream>>>(
        WB + 393216, Y, (void*)WY, zb, ST, CIDIM, CIDIM, CIDIM, LDIM, 0, LCI, CL);

    bn_finalize<<<2, 256, 0, stream>>>(ST);
    bn_apply_kernel<<<dim3(NB * CDIM * LDIM / 4 / 256), 256, 0, stream>>>(
        WY, ST, x, bng, bnb, out);
}